// Round 1
// baseline (1652.720 us; speedup 1.0000x reference)
//
#include <hip/hip_runtime.h>
#include <hip/hip_bf16.h>
#include <math.h>

#define N_NODES 49152
#define N_EDGES 196608
#define NB      2048
#define HIDDEN  256
#define LAT     128
#define FHID    256
#define NFLOWS  4
#define MA      38
#define NNF_    38
#define NEF_    4
#define GPB     8   // graphs per block in the flows kernel

// ---------------- init / CSR build ----------------

__global__ void k_init(int* __restrict__ cursor, int* __restrict__ gstart, int* __restrict__ gcnt){
    int i = blockIdx.x*256 + threadIdx.x;
    if (i < N_NODES) cursor[i] = 0;
    if (i < NB){ gstart[i] = 0x7fffffff; gcnt[i] = 0; }
}

__global__ void k_embed(const int* __restrict__ x, const float* __restrict__ emb, float* __restrict__ h){
    int i = blockIdx.x; int c = threadIdx.x;
    h[(size_t)i*HIDDEN + c] = emb[x[i]*HIDDEN + c];
}

__global__ void k_deg(const int* __restrict__ dst, int* __restrict__ cursor){
    int e = blockIdx.x*256 + threadIdx.x;
    if (e < N_EDGES) atomicAdd(&cursor[dst[e]], 1);
}

__global__ void k_meta(const int* __restrict__ batch, int* __restrict__ gstart, int* __restrict__ gcnt){
    int i = blockIdx.x*256 + threadIdx.x;
    if (i < N_NODES){ int b = batch[i]; atomicMin(&gstart[b], i); atomicAdd(&gcnt[b], 1); }
}

// single block, 1024 threads, 48 elements each: exclusive scan of degrees -> offsets
__global__ __launch_bounds__(1024) void k_scan(int* __restrict__ cursor, int* __restrict__ offs){
    __shared__ int part[1024];
    const int tid = threadIdx.x;
    const int CH = N_NODES/1024; // 48
    int local[48];
    int s = 0;
    int base = tid*CH;
    for (int j=0;j<CH;j++){ local[j] = cursor[base+j]; s += local[j]; }
    part[tid] = s;
    __syncthreads();
    for (int off=1; off<1024; off<<=1){
        int v = (tid>=off) ? part[tid-off] : 0;
        __syncthreads();
        part[tid] += v;
        __syncthreads();
    }
    int excl = (tid==0) ? 0 : part[tid-1];
    for (int j=0;j<CH;j++){ offs[base+j] = excl; excl += local[j]; cursor[base+j] = 0; }
    if (tid == 1023) offs[N_NODES] = excl; // == N_EDGES
}

__global__ void k_scatter(const int* __restrict__ src, const int* __restrict__ dst, const int* __restrict__ attr,
                          const int* __restrict__ offs, int* __restrict__ cursor, int* __restrict__ epack){
    int e = blockIdx.x*256 + threadIdx.x;
    if (e < N_EDGES){
        int d = dst[e];
        int pos = atomicAdd(&cursor[d], 1);
        epack[offs[d] + pos] = (src[e] & 0xffff) | (attr[e] << 16);  // src < 2^16, attr < 4
    }
}

// ---------------- message aggregation:  t[i] = h[i] + sum_{e: dst=i} relu(h[src]+edge_emb[attr]) ----------------

__global__ void k_aggr(const float* __restrict__ h, const float* __restrict__ eemb,
                       const int* __restrict__ offs, const int* __restrict__ epack,
                       float* __restrict__ t){
    int i = blockIdx.x; int c = threadIdx.x;
    float s = h[(size_t)i*HIDDEN + c];
    int e0 = offs[i], e1 = offs[i+1];
    for (int j=e0;j<e1;j++){
        int p = epack[j];
        float v = h[(size_t)(p & 0xffff)*HIDDEN + c] + eemb[(p>>16)*HIDDEN + c];
        s += fmaxf(v, 0.f);
    }
    t[(size_t)i*HIDDEN + c] = s;
}

// ---------------- generic fp32 GEMM:  C[M,N] = act(A[M,K] @ W[N,K]^T + bias) ----------------
// TILE: 64 rows x 256 cols per block, K chunk 32. grid = (ceil(N/256), M/64).
// In-place safe when gridDim.x==1 (each block reads only its own 64 rows, writes only in epilogue).

__global__ __launch_bounds__(256) void gemm_bias_act(
    const float* __restrict__ A, int lda,
    const float* __restrict__ W,      // [N][K] row-major
    const float* __restrict__ bias,
    float* __restrict__ C, int ldc,
    int M, int N, int K, int do_relu)
{
    __shared__ __align__(16) float As[32][68];
    __shared__ __align__(16) float Bs[32][260];
    const int tid = threadIdx.x;
    const int tx  = tid & 15;
    const int ty  = tid >> 4;
    const int row0 = blockIdx.y * 64;
    const int n0   = blockIdx.x * 256;
    const int kk_g = tid & 7;   // k-offset group (x4)
    const int rr   = tid >> 3;  // 0..31

    float acc[4][16];
    #pragma unroll
    for (int r=0;r<4;r++)
        #pragma unroll
        for (int i=0;i<16;i++) acc[r][i]=0.f;

    for (int k0 = 0; k0 < K; k0 += 32) {
        // stage A (64x32, transposed into As[k][row])
        {
            const float4 a0 = *(const float4*)(A + (size_t)(row0 + rr     ) * lda + k0 + kk_g*4);
            const float4 a1 = *(const float4*)(A + (size_t)(row0 + rr + 32) * lda + k0 + kk_g*4);
            As[kk_g*4+0][rr] = a0.x; As[kk_g*4+1][rr] = a0.y; As[kk_g*4+2][rr] = a0.z; As[kk_g*4+3][rr] = a0.w;
            As[kk_g*4+0][rr+32] = a1.x; As[kk_g*4+1][rr+32] = a1.y; As[kk_g*4+2][rr+32] = a1.z; As[kk_g*4+3][rr+32] = a1.w;
        }
        // stage B (32 k x 256 cols): thread tid handles column n0+tid
        {
            const int col = n0 + tid;
            if (col < N) {
                const float* wrow = W + (size_t)col * K + k0;
                #pragma unroll
                for (int q=0;q<8;q++){
                    float4 b = *(const float4*)(wrow + q*4);
                    Bs[q*4+0][tid]=b.x; Bs[q*4+1][tid]=b.y; Bs[q*4+2][tid]=b.z; Bs[q*4+3][tid]=b.w;
                }
            } else {
                #pragma unroll
                for (int q=0;q<8;q++){
                    Bs[q*4+0][tid]=0.f; Bs[q*4+1][tid]=0.f; Bs[q*4+2][tid]=0.f; Bs[q*4+3][tid]=0.f;
                }
            }
        }
        __syncthreads();
        #pragma unroll
        for (int k=0;k<32;k++){
            const float4 av = *(const float4*)&As[k][ty*4];
            const float a[4] = {av.x, av.y, av.z, av.w};
            #pragma unroll
            for (int i=0;i<4;i++){
                const float4 bv = *(const float4*)&Bs[k][i*64 + tx*4];
                const float b[4] = {bv.x, bv.y, bv.z, bv.w};
                #pragma unroll
                for (int r=0;r<4;r++){
                    acc[r][i*4+0] += a[r]*b[0];
                    acc[r][i*4+1] += a[r]*b[1];
                    acc[r][i*4+2] += a[r]*b[2];
                    acc[r][i*4+3] += a[r]*b[3];
                }
            }
        }
        __syncthreads();
    }

    // epilogue
    #pragma unroll
    for (int i=0;i<4;i++){
        const int col = n0 + i*64 + tx*4;
        if (col < N){
            const float4 bv = *(const float4*)(bias + col);
            const float bb[4] = {bv.x, bv.y, bv.z, bv.w};
            #pragma unroll
            for (int r=0;r<4;r++){
                const int row = row0 + ty*4 + r;
                float4 v;
                v.x = acc[r][i*4+0] + bb[0];
                v.y = acc[r][i*4+1] + bb[1];
                v.z = acc[r][i*4+2] + bb[2];
                v.w = acc[r][i*4+3] + bb[3];
                if (do_relu){
                    v.x = fmaxf(v.x,0.f); v.y = fmaxf(v.y,0.f);
                    v.z = fmaxf(v.z,0.f); v.w = fmaxf(v.w,0.f);
                }
                *(float4*)(C + (size_t)row*ldc + col) = v;
            }
        }
    }
}

// ---------------- pooling + mu/logvar/z0 ----------------

__global__ void k_pool(const float* __restrict__ h, const int* __restrict__ gstart,
                       const int* __restrict__ gcnt, float* __restrict__ hg){
    int b = blockIdx.x; int c = threadIdx.x;
    int s0 = gstart[b]; int n = gcnt[b];
    float s = 0.f;
    for (int j=0;j<n;j++) s += h[(size_t)(s0+j)*HIDDEN + c];
    hg[(size_t)b*HIDDEN + c] = s;
}

__global__ __launch_bounds__(128) void k_mulv(const float* __restrict__ hg,
    const float* __restrict__ mu_w, const float* __restrict__ mu_b,
    const float* __restrict__ lv_w, const float* __restrict__ lv_b,
    const float* __restrict__ eps,
    float* __restrict__ mu_o, float* __restrict__ lv_o, float* __restrict__ z0_o){
    __shared__ float hrow[HIDDEN];
    int b = blockIdx.x; int l = threadIdx.x;
    hrow[l]       = hg[(size_t)b*HIDDEN + l];
    hrow[l+128]   = hg[(size_t)b*HIDDEN + l + 128];
    __syncthreads();
    float m = mu_b[l], v = lv_b[l];
    const float* wm = mu_w + (size_t)l*HIDDEN;
    const float* wv = lv_w + (size_t)l*HIDDEN;
    #pragma unroll 8
    for (int k=0;k<HIDDEN;k++){ m += hrow[k]*wm[k]; v += hrow[k]*wv[k]; }
    mu_o[(size_t)b*LAT + l] = m;
    lv_o[(size_t)b*LAT + l] = v;
    z0_o[(size_t)b*LAT + l] = m + eps[(size_t)b*LAT + l]*expf(0.5f*v);
}

// ---------------- flows (all 4, fused; MADE masks from indices) ----------------

__global__ __launch_bounds__(256) void k_flows(
    const float* __restrict__ z0,
    const float* __restrict__ fw1, const float* __restrict__ fb1,
    const float* __restrict__ fw2, const float* __restrict__ fb2,
    float* __restrict__ zK, float* __restrict__ sld)
{
    __shared__ __align__(16) float zT[LAT][GPB];       // 128 x 8
    __shared__ __align__(16) float h1T[FHID][GPB];     // 256 x 8
    __shared__ __align__(16) float outT[2*LAT][GPB];   // 256 x 8
    const int tid = threadIdx.x;
    const int g0  = blockIdx.x * GPB;

    // load z0 tile
    #pragma unroll
    for (int q=0;q<4;q++){
        int idx = q*256 + tid;
        int g = idx & 7, l = idx >> 3;
        zT[l][g] = z0[(size_t)(g0+g)*LAT + l];
    }
    float ld[GPB];
    #pragma unroll
    for (int g=0;g<GPB;g++) ld[g] = 0.f;
    __syncthreads();

    for (int kf=0; kf<NFLOWS; kf++){
        const float* w1 = fw1 + (size_t)kf*FHID*LAT;
        const float* b1 = fb1 + (size_t)kf*FHID;
        const float* w2 = fw2 + (size_t)kf*2*LAT*FHID;
        const float* b2 = fb2 + (size_t)kf*2*LAT;

        // h1[o] = relu(b1[o] + sum_{kk<=o%127} z[kk]*w1[o][kk])
        {
            const int o = tid;
            const int upper = o % 127;
            float acc[GPB];
            const float bb = b1[o];
            #pragma unroll
            for (int g=0;g<GPB;g++) acc[g] = bb;
            for (int kk=0; kk<=upper; kk++){
                const float w = w1[(size_t)o*LAT + kk];
                const float4 za = *(const float4*)&zT[kk][0];
                const float4 zb = *(const float4*)&zT[kk][4];
                acc[0] += w*za.x; acc[1] += w*za.y; acc[2] += w*za.z; acc[3] += w*za.w;
                acc[4] += w*zb.x; acc[5] += w*zb.y; acc[6] += w*zb.z; acc[7] += w*zb.w;
            }
            #pragma unroll
            for (int g=0;g<GPB;g++) h1T[o][g] = fmaxf(acc[g], 0.f);
        }
        __syncthreads();
        // out[o] = b2[o] + sum_{h: h%127 < o%128} h1[h]*w2[o][h]
        {
            const int o = tid;
            const int L = o & 127;
            float acc[GPB];
            const float bb = b2[o];
            #pragma unroll
            for (int g=0;g<GPB;g++) acc[g] = bb;
            for (int hh=0; hh<FHID; hh++){
                const int hm = (hh < 127) ? hh : ((hh < 254) ? hh - 127 : hh - 254);
                if (hm < L){
                    const float w = w2[(size_t)o*FHID + hh];
                    const float4 ha = *(const float4*)&h1T[hh][0];
                    const float4 hb = *(const float4*)&h1T[hh][4];
                    acc[0] += w*ha.x; acc[1] += w*ha.y; acc[2] += w*ha.z; acc[3] += w*ha.w;
                    acc[4] += w*hb.x; acc[5] += w*hb.y; acc[6] += w*hb.z; acc[7] += w*hb.w;
                }
            }
            #pragma unroll
            for (int g=0;g<GPB;g++) outT[o][g] = acc[g];
        }
        __syncthreads();
        // z update + log-det
        if (tid < LAT){
            const int l = tid;
            #pragma unroll
            for (int g=0;g<GPB;g++){
                const float m = outT[l][g];
                const float s = outT[l+LAT][g];
                const float gate = 1.f/(1.f + expf(-s));
                zT[l][g] = gate*zT[l][g] + (1.f-gate)*m;
                ld[g] += logf(gate + 1e-8f);
            }
        }
        __syncthreads();
    }

    // write zK
    #pragma unroll
    for (int q=0;q<4;q++){
        int idx = q*256 + tid;
        int g = idx & 7, l = idx >> 3;
        zK[(size_t)(g0+g)*LAT + l] = zT[l][g];
    }
    // reduce log-det over latent dim
    if (tid < LAT){
        #pragma unroll
        for (int g=0;g<GPB;g++) outT[tid][g] = ld[g];
    }
    __syncthreads();
    for (int st=64; st>0; st>>=1){
        if (tid < st){
            #pragma unroll
            for (int g=0;g<GPB;g++) outT[tid][g] += outT[tid+st][g];
        }
        __syncthreads();
    }
    if (tid < GPB) sld[g0 + tid] = outT[0][tid];
}

// ---------------- edge-logits symmetrize ----------------

__global__ void k_sym(const float* __restrict__ raw, float* __restrict__ outp){
    int idx = blockIdx.x*256 + threadIdx.x;     // (b, i, j)
    const int total = NB*MA*MA;
    if (idx >= total) return;
    int b = idx / (MA*MA);
    int rem = idx - b*(MA*MA);
    int i = rem / MA;
    int j = rem - i*MA;
    const size_t base = (size_t)b*(MA*MA*NEF_);
    const float4 a  = *(const float4*)(raw + base + (size_t)(i*MA + j)*NEF_);
    const float4 bt = *(const float4*)(raw + base + (size_t)(j*MA + i)*NEF_);
    float4 r;
    r.x = (a.x + bt.x)*0.5f;
    r.y = (a.y + bt.y)*0.5f;
    r.z = (a.z + bt.z)*0.5f;
    r.w = (a.w + bt.w)*0.5f;
    *(float4*)(outp + base + (size_t)(i*MA + j)*NEF_) = r;
}

// ---------------- launch ----------------

extern "C" void kernel_launch(void* const* d_in, const int* in_sizes, int n_in,
                              void* d_out, int out_size, void* d_ws, size_t ws_size,
                              hipStream_t stream){
    (void)in_sizes; (void)n_in; (void)out_size; (void)ws_size;
    const int*   x        = (const int*)d_in[0];
    const int*   eidx     = (const int*)d_in[1];
    const int*   eattr    = (const int*)d_in[2];
    const int*   batch    = (const int*)d_in[3];
    const float* eps      = (const float*)d_in[4];
    const float* node_emb = (const float*)d_in[5];
    const float* edge_emb = (const float*)d_in[6];
    const float* conv_w1  = (const float*)d_in[7];
    const float* conv_b1  = (const float*)d_in[8];
    const float* conv_w2  = (const float*)d_in[9];
    const float* conv_b2  = (const float*)d_in[10];
    const float* mu_w     = (const float*)d_in[11];
    const float* mu_b     = (const float*)d_in[12];
    const float* lv_w     = (const float*)d_in[13];
    const float* lv_b     = (const float*)d_in[14];
    const float* fw1      = (const float*)d_in[15];
    const float* fb1      = (const float*)d_in[16];
    const float* fw2      = (const float*)d_in[17];
    const float* fb2      = (const float*)d_in[18];
    const float* dn_w1    = (const float*)d_in[19];
    const float* dn_b1    = (const float*)d_in[20];
    const float* dn_w2    = (const float*)d_in[21];
    const float* dn_b2    = (const float*)d_in[22];
    const float* de_w1    = (const float*)d_in[23];
    const float* de_b1    = (const float*)d_in[24];
    const float* de_w2    = (const float*)d_in[25];
    const float* de_b2    = (const float*)d_in[26];

    float* out = (float*)d_out;
    const size_t off_node = 0;
    const size_t off_edge = (size_t)NB*MA*NNF_;
    const size_t off_mu   = off_edge + (size_t)NB*MA*MA*NEF_;
    const size_t off_lv   = off_mu + (size_t)NB*LAT;
    const size_t off_z0   = off_lv + (size_t)NB*LAT;
    const size_t off_zk   = off_z0 + (size_t)NB*LAT;
    const size_t off_sld  = off_zk + (size_t)NB*LAT;

    char* p = (char*)d_ws;
    auto alloc = [&](size_t bytes)->char*{ char* r = p; p += (bytes + 255) & ~(size_t)255; return r; };
    float* bufA   = (float*)alloc((size_t)N_NODES*HIDDEN*4);   // h
    float* bufB   = (float*)alloc((size_t)N_NODES*HIDDEN*4);   // t/u in-place; later edge_raw
    int*   offs   = (int*)  alloc((size_t)(N_NODES+1)*4);
    int*   cursor = (int*)  alloc((size_t)N_NODES*4);
    int*   epack  = (int*)  alloc((size_t)N_EDGES*4);
    int*   gstart = (int*)  alloc((size_t)NB*4);
    int*   gcnt   = (int*)  alloc((size_t)NB*4);
    float* hg     = (float*)alloc((size_t)NB*HIDDEN*4);
    float* hn     = (float*)alloc((size_t)NB*256*4);
    float* he     = (float*)alloc((size_t)NB*512*4);

    const int* esrc = eidx;
    const int* edst = eidx + N_EDGES;

    k_init   <<<(N_NODES+255)/256, 256, 0, stream>>>(cursor, gstart, gcnt);
    k_embed  <<<N_NODES, HIDDEN, 0, stream>>>(x, node_emb, bufA);
    k_deg    <<<(N_EDGES+255)/256, 256, 0, stream>>>(edst, cursor);
    k_meta   <<<(N_NODES+255)/256, 256, 0, stream>>>(batch, gstart, gcnt);
    k_scan   <<<1, 1024, 0, stream>>>(cursor, offs);
    k_scatter<<<(N_EDGES+255)/256, 256, 0, stream>>>(esrc, edst, eattr, offs, cursor, epack);

    for (int k=0;k<4;k++){
        k_aggr<<<N_NODES, HIDDEN, 0, stream>>>(bufA, edge_emb, offs, epack, bufB);
        gemm_bias_act<<<dim3(1, N_NODES/64), 256, 0, stream>>>(
            bufB, HIDDEN, conv_w1 + (size_t)k*HIDDEN*HIDDEN, conv_b1 + (size_t)k*HIDDEN,
            bufB, HIDDEN, N_NODES, HIDDEN, HIDDEN, 1);
        gemm_bias_act<<<dim3(1, N_NODES/64), 256, 0, stream>>>(
            bufB, HIDDEN, conv_w2 + (size_t)k*HIDDEN*HIDDEN, conv_b2 + (size_t)k*HIDDEN,
            bufA, HIDDEN, N_NODES, HIDDEN, HIDDEN, 1);
    }

    k_pool<<<NB, HIDDEN, 0, stream>>>(bufA, gstart, gcnt, hg);
    k_mulv<<<NB, LAT, 0, stream>>>(hg, mu_w, mu_b, lv_w, lv_b, eps,
                                   out+off_mu, out+off_lv, out+off_z0);
    k_flows<<<NB/GPB, 256, 0, stream>>>(out+off_z0, fw1, fb1, fw2, fb2,
                                        out+off_zk, out+off_sld);

    // decoders
    gemm_bias_act<<<dim3(1, NB/64), 256, 0, stream>>>(out+off_zk, LAT, dn_w1, dn_b1, hn, 256, NB, 256, LAT, 1);
    gemm_bias_act<<<dim3(6, NB/64), 256, 0, stream>>>(hn, 256, dn_w2, dn_b2, out+off_node, MA*NNF_, NB, MA*NNF_, 256, 0);
    gemm_bias_act<<<dim3(2, NB/64), 256, 0, stream>>>(out+off_zk, LAT, de_w1, de_b1, he, 512, NB, 512, LAT, 1);
    gemm_bias_act<<<dim3(23, NB/64), 256, 0, stream>>>(he, 512, de_w2, de_b2, bufB, MA*MA*NEF_, NB, MA*MA*NEF_, 512, 0);
    k_sym<<<(NB*MA*MA + 255)/256, 256, 0, stream>>>(bufB, out + off_edge);
}

// Round 2
// 1213.246 us; speedup vs baseline: 1.3622x; 1.3622x over previous
//
#include <hip/hip_runtime.h>
#include <hip/hip_bf16.h>
#include <math.h>
#include <stdint.h>

#define N_NODES 49152
#define N_EDGES 196608
#define NB      2048
#define HIDDEN  256
#define LAT     128
#define FHID    256
#define NFLOWS  4
#define MA      38
#define NNF_    38
#define NEF_    4
#define GPB     8

typedef __attribute__((ext_vector_type(8))) short bf16x8;
typedef __attribute__((ext_vector_type(4))) float f32x4;

// ---------- hi/lo bf16 packing (hi in top 16 bits, lo in bottom 16) ----------
__device__ inline uint32_t bf16_rne_bits(float v){
    uint32_t u = __float_as_uint(v);
    u += 0x7fffu + ((u >> 16) & 1u);
    return u & 0xffff0000u;
}
__device__ inline uint32_t pack_hl(float v){
    uint32_t hu = bf16_rne_bits(v);
    float r = v - __uint_as_float(hu);
    uint32_t lu = bf16_rne_bits(r);
    return hu | (lu >> 16);
}
__device__ inline float unpack_hl(uint32_t u){
    return __uint_as_float(u & 0xffff0000u) + __uint_as_float(u << 16);
}

// ---------------- init / CSR build ----------------

__global__ void k_init(int* __restrict__ cursor, int* __restrict__ gstart, int* __restrict__ gcnt){
    int i = blockIdx.x*256 + threadIdx.x;
    if (i < N_NODES) cursor[i] = 0;
    if (i < NB){ gstart[i] = 0x7fffffff; gcnt[i] = 0; }
}

__global__ void k_embed(const int* __restrict__ x, const float* __restrict__ emb, uint32_t* __restrict__ h){
    int i = blockIdx.x; int c = threadIdx.x;
    h[(size_t)i*HIDDEN + c] = pack_hl(emb[x[i]*HIDDEN + c]);
}

__global__ void k_deg(const int* __restrict__ dst, int* __restrict__ cursor){
    int e = blockIdx.x*256 + threadIdx.x;
    if (e < N_EDGES) atomicAdd(&cursor[dst[e]], 1);
}

__global__ void k_meta(const int* __restrict__ batch, int* __restrict__ gstart, int* __restrict__ gcnt){
    int i = blockIdx.x*256 + threadIdx.x;
    if (i < N_NODES){ int b = batch[i]; atomicMin(&gstart[b], i); atomicAdd(&gcnt[b], 1); }
}

__global__ __launch_bounds__(1024) void k_scan(int* __restrict__ cursor, int* __restrict__ offs){
    __shared__ int part[1024];
    const int tid = threadIdx.x;
    const int CH = N_NODES/1024; // 48
    int local[48];
    int s = 0;
    int base = tid*CH;
    for (int j=0;j<CH;j++){ local[j] = cursor[base+j]; s += local[j]; }
    part[tid] = s;
    __syncthreads();
    for (int off=1; off<1024; off<<=1){
        int v = (tid>=off) ? part[tid-off] : 0;
        __syncthreads();
        part[tid] += v;
        __syncthreads();
    }
    int excl = (tid==0) ? 0 : part[tid-1];
    for (int j=0;j<CH;j++){ offs[base+j] = excl; excl += local[j]; cursor[base+j] = 0; }
    if (tid == 1023) offs[N_NODES] = excl;
}

__global__ void k_scatter(const int* __restrict__ src, const int* __restrict__ dst, const int* __restrict__ attr,
                          const int* __restrict__ offs, int* __restrict__ cursor, int* __restrict__ epack){
    int e = blockIdx.x*256 + threadIdx.x;
    if (e < N_EDGES){
        int d = dst[e];
        int pos = atomicAdd(&cursor[d], 1);
        epack[offs[d] + pos] = (src[e] & 0xffff) | (attr[e] << 16);
    }
}

// ---------------- message aggregation (packed hi/lo activations) ----------------

__global__ void k_aggr(const uint32_t* __restrict__ h, const float* __restrict__ eemb,
                       const int* __restrict__ offs, const int* __restrict__ epack,
                       uint32_t* __restrict__ t){
    int i = blockIdx.x; int c = threadIdx.x;
    float s = unpack_hl(h[(size_t)i*HIDDEN + c]);
    int e0 = offs[i], e1 = offs[i+1];
    for (int j=e0;j<e1;j++){
        int p = epack[j];
        float v = unpack_hl(h[(size_t)(p & 0xffff)*HIDDEN + c]) + eemb[(p>>16)*HIDDEN + c];
        s += fmaxf(v, 0.f);
    }
    t[(size_t)i*HIDDEN + c] = pack_hl(s);
}

// ---------------- weight / activation converters ----------------

__global__ void k_cvt_pack(const float* __restrict__ s, uint32_t* __restrict__ d, int n){
    int i = blockIdx.x*256 + threadIdx.x;
    if (i < n) d[i] = pack_hl(s[i]);
}
__global__ void k_cvt_b16(const float* __restrict__ s, uint16_t* __restrict__ d, int n){
    int i = blockIdx.x*256 + threadIdx.x;
    if (i < n) d[i] = (uint16_t)(bf16_rne_bits(s[i]) >> 16);
}

// ---------------- MFMA GEMM:  C[M,N] = act(A[M,K] @ W[N,K]^T + bias) ----------------
// SPLIT=1: A,W are packed u32 (hi|lo); 3 MFMAs/tile (hi*hi + hi*lo + lo*hi).
// SPLIT=0: A,W are plain bf16; 1 MFMA/tile.
// OUTM: 0 = packed u32 out, 1 = bf16 out, 2 = fp32 out.
// Block tile 64 rows x 256 cols (4 waves, each 64x64). A staged in LDS via
// global_load_lds(16B) with XOR granule swizzle; B fragments from global (L2).

__device__ inline void unpack_frag(const uint4& x, const uint4& y, bf16x8& hi, bf16x8& lo){
    union { bf16x8 v; uint32_t u[4]; } H, L;
    H.u[0] = __builtin_amdgcn_perm(x.y, x.x, 0x07060302u);
    H.u[1] = __builtin_amdgcn_perm(x.w, x.z, 0x07060302u);
    H.u[2] = __builtin_amdgcn_perm(y.y, y.x, 0x07060302u);
    H.u[3] = __builtin_amdgcn_perm(y.w, y.z, 0x07060302u);
    L.u[0] = __builtin_amdgcn_perm(x.y, x.x, 0x05040100u);
    L.u[1] = __builtin_amdgcn_perm(x.w, x.z, 0x05040100u);
    L.u[2] = __builtin_amdgcn_perm(y.y, y.x, 0x05040100u);
    L.u[3] = __builtin_amdgcn_perm(y.w, y.z, 0x05040100u);
    hi = H.v; lo = L.v;
}

template<int SPLIT, int OUTM>
__global__ __launch_bounds__(256) void mfma_gemm(
    const void* __restrict__ Ap, const void* __restrict__ Wp,
    const float* __restrict__ bias, void* __restrict__ Cp,
    int M, int N, int K, int relu)
{
    extern __shared__ __align__(16) char smem[];
    const int tid  = threadIdx.x;
    const int wave = tid >> 6;
    const int lane = tid & 63;
    const int l15  = lane & 15;
    const int lq   = lane >> 4;     // 0..3
    const int l7   = lane & 7;
    const int row0 = blockIdx.y * 64;
    const int n0   = blockIdx.x * 256;
    const int ELB  = SPLIT ? 4 : 2;
    const int KC   = (K < 256) ? K : 256;
    const int GR   = (KC * ELB) >> 4;                  // 16B granules per row
    const int rsh  = (GR == 64) ? 6 : ((GR == 32) ? 5 : 4);

    f32x4 acc[4][4];
    #pragma unroll
    for (int mt=0;mt<4;mt++)
        #pragma unroll
        for (int nt=0;nt<4;nt++) acc[mt][nt] = (f32x4)(0.f);

    const char* Ab = (const char*)Ap;
    const char* Wb = (const char*)Wp;

    for (int kbase = 0; kbase < K; kbase += KC) {
        // ---- stage A chunk into LDS (swizzled) ----
        const int rounds = GR >> 2;
        for (int it = 0; it < rounds; ++it) {
            int sbase = it*256 + wave*64;
            int s  = sbase + lane;
            int m  = s >> rsh;
            int gl = (s & (GR-1)) ^ (m & 7);
            const char* gp = Ab + ((size_t)(row0+m)*K + kbase)*ELB + gl*16;
            __builtin_amdgcn_global_load_lds(
                (const __attribute__((address_space(1))) uint32_t*)gp,
                (__attribute__((address_space(3))) uint32_t*)(smem + sbase*16),
                16, 0, 0);
        }
        __syncthreads();

        // ---- compute over this K chunk ----
        for (int kc = 0; kc < (KC >> 5); ++kc) {
            bf16x8 bhi[4], blo[4];
            #pragma unroll
            for (int nt=0;nt<4;nt++){
                int n = n0 + wave*64 + nt*16 + l15;
                if (n >= N) n = N-1;
                if (SPLIT){
                    const uint4* wp4 = (const uint4*)(Wb + ((size_t)n*K + kbase + kc*32 + lq*8)*4);
                    uint4 xx = wp4[0], yy = wp4[1];
                    unpack_frag(xx, yy, bhi[nt], blo[nt]);
                } else {
                    bhi[nt] = *(const bf16x8*)(Wb + ((size_t)n*K + kbase + kc*32 + lq*8)*2);
                }
            }
            #pragma unroll
            for (int mt=0;mt<4;mt++){
                const int mb = (mt*16 + l15) << rsh;
                if (SPLIT){
                    int g0 = kc*8 + lq*2;
                    uint4 xx = *(const uint4*)(smem + (size_t)(mb + ((g0  ) ^ l7))*16);
                    uint4 yy = *(const uint4*)(smem + (size_t)(mb + ((g0+1) ^ l7))*16);
                    bf16x8 ahi, alo;
                    unpack_frag(xx, yy, ahi, alo);
                    #pragma unroll
                    for (int nt=0;nt<4;nt++){
                        acc[mt][nt] = __builtin_amdgcn_mfma_f32_16x16x32_bf16(ahi, bhi[nt], acc[mt][nt], 0, 0, 0);
                        acc[mt][nt] = __builtin_amdgcn_mfma_f32_16x16x32_bf16(ahi, blo[nt], acc[mt][nt], 0, 0, 0);
                        acc[mt][nt] = __builtin_amdgcn_mfma_f32_16x16x32_bf16(alo, bhi[nt], acc[mt][nt], 0, 0, 0);
                    }
                } else {
                    int g = kc*4 + lq;
                    bf16x8 a = *(const bf16x8*)(smem + (size_t)(mb + (g ^ l7))*16);
                    #pragma unroll
                    for (int nt=0;nt<4;nt++){
                        acc[mt][nt] = __builtin_amdgcn_mfma_f32_16x16x32_bf16(a, bhi[nt], acc[mt][nt], 0, 0, 0);
                    }
                }
            }
        }
        __syncthreads();
    }

    // ---- epilogue: bias/act, repack via LDS, coalesced store ----
    char* rs = smem + wave*16384;         // wave-private 64x64 region
    const int colbase = n0 + wave*64;
    #pragma unroll
    for (int mt=0;mt<4;mt++){
        #pragma unroll
        for (int nt=0;nt<4;nt++){
            int cl = nt*16 + l15;
            int col = colbase + cl;
            float bb = bias[col < N ? col : N-1];
            #pragma unroll
            for (int reg=0;reg<4;reg++){
                int r = mt*16 + lq*4 + reg;
                float v = acc[mt][nt][reg] + bb;
                if (relu) v = fmaxf(v, 0.f);
                if (OUTM == 0) ((uint32_t*)rs)[r*64 + cl] = pack_hl(v);
                else           ((float*)rs)[r*64 + cl] = v;
            }
        }
    }
    __syncthreads();
    for (int it = 0; it < 32; ++it) {
        int r   = it*2 + (lane>>5);
        int clp = lane & 31;
        int col = colbase + clp*2;
        if (col < N){
            if (OUTM == 0){
                uint2 d = *(const uint2*)((const uint32_t*)rs + r*64 + clp*2);
                *(uint2*)((uint32_t*)Cp + (size_t)(row0+r)*N + col) = d;
            } else if (OUTM == 1){
                const float* f = (const float*)rs + r*64 + clp*2;
                uint32_t b0 = bf16_rne_bits(f[0]) >> 16;
                uint32_t b1 = bf16_rne_bits(f[1]) >> 16;
                *(uint32_t*)((char*)Cp + ((size_t)(row0+r)*N + col)*2) = b0 | (b1 << 16);
            } else {
                float2 d = *(const float2*)((const float*)rs + r*64 + clp*2);
                *(float2*)((float*)Cp + (size_t)(row0+r)*N + col) = d;
            }
        }
    }
}

// ---------------- pooling + mu/logvar/z0 ----------------

__global__ void k_pool(const uint32_t* __restrict__ h, const int* __restrict__ gstart,
                       const int* __restrict__ gcnt, float* __restrict__ hg){
    int b = blockIdx.x; int c = threadIdx.x;
    int s0 = gstart[b]; int n = gcnt[b];
    float s = 0.f;
    for (int j=0;j<n;j++) s += unpack_hl(h[(size_t)(s0+j)*HIDDEN + c]);
    hg[(size_t)b*HIDDEN + c] = s;
}

__global__ __launch_bounds__(128) void k_mulv(const float* __restrict__ hg,
    const float* __restrict__ mu_w, const float* __restrict__ mu_b,
    const float* __restrict__ lv_w, const float* __restrict__ lv_b,
    const float* __restrict__ eps,
    float* __restrict__ mu_o, float* __restrict__ lv_o, float* __restrict__ z0_o){
    __shared__ float hrow[HIDDEN];
    int b = blockIdx.x; int l = threadIdx.x;
    hrow[l]       = hg[(size_t)b*HIDDEN + l];
    hrow[l+128]   = hg[(size_t)b*HIDDEN + l + 128];
    __syncthreads();
    float m = mu_b[l], v = lv_b[l];
    const float* wm = mu_w + (size_t)l*HIDDEN;
    const float* wv = lv_w + (size_t)l*HIDDEN;
    #pragma unroll 8
    for (int k=0;k<HIDDEN;k++){ m += hrow[k]*wm[k]; v += hrow[k]*wv[k]; }
    mu_o[(size_t)b*LAT + l] = m;
    lv_o[(size_t)b*LAT + l] = v;
    z0_o[(size_t)b*LAT + l] = m + eps[(size_t)b*LAT + l]*expf(0.5f*v);
}

// ---------------- flows ----------------

__global__ __launch_bounds__(256) void k_flows(
    const float* __restrict__ z0,
    const float* __restrict__ fw1, const float* __restrict__ fb1,
    const float* __restrict__ fw2, const float* __restrict__ fb2,
    float* __restrict__ zK, float* __restrict__ sld)
{
    __shared__ __align__(16) float zT[LAT][GPB];
    __shared__ __align__(16) float h1T[FHID][GPB];
    __shared__ __align__(16) float outT[2*LAT][GPB];
    const int tid = threadIdx.x;
    const int g0  = blockIdx.x * GPB;

    #pragma unroll
    for (int q=0;q<4;q++){
        int idx = q*256 + tid;
        int g = idx & 7, l = idx >> 3;
        zT[l][g] = z0[(size_t)(g0+g)*LAT + l];
    }
    float ld[GPB];
    #pragma unroll
    for (int g=0;g<GPB;g++) ld[g] = 0.f;
    __syncthreads();

    for (int kf=0; kf<NFLOWS; kf++){
        const float* w1 = fw1 + (size_t)kf*FHID*LAT;
        const float* b1 = fb1 + (size_t)kf*FHID;
        const float* w2 = fw2 + (size_t)kf*2*LAT*FHID;
        const float* b2 = fb2 + (size_t)kf*2*LAT;
        {
            const int o = tid;
            const int upper = o % 127;
            float acc[GPB];
            const float bb = b1[o];
            #pragma unroll
            for (int g=0;g<GPB;g++) acc[g] = bb;
            for (int kk=0; kk<=upper; kk++){
                const float w = w1[(size_t)o*LAT + kk];
                const float4 za = *(const float4*)&zT[kk][0];
                const float4 zb = *(const float4*)&zT[kk][4];
                acc[0] += w*za.x; acc[1] += w*za.y; acc[2] += w*za.z; acc[3] += w*za.w;
                acc[4] += w*zb.x; acc[5] += w*zb.y; acc[6] += w*zb.z; acc[7] += w*zb.w;
            }
            #pragma unroll
            for (int g=0;g<GPB;g++) h1T[o][g] = fmaxf(acc[g], 0.f);
        }
        __syncthreads();
        {
            const int o = tid;
            const int L = o & 127;
            float acc[GPB];
            const float bb = b2[o];
            #pragma unroll
            for (int g=0;g<GPB;g++) acc[g] = bb;
            for (int hh=0; hh<FHID; hh++){
                const int hm = (hh < 127) ? hh : ((hh < 254) ? hh - 127 : hh - 254);
                if (hm < L){
                    const float w = w2[(size_t)o*FHID + hh];
                    const float4 ha = *(const float4*)&h1T[hh][0];
                    const float4 hb = *(const float4*)&h1T[hh][4];
                    acc[0] += w*ha.x; acc[1] += w*ha.y; acc[2] += w*ha.z; acc[3] += w*ha.w;
                    acc[4] += w*hb.x; acc[5] += w*hb.y; acc[6] += w*hb.z; acc[7] += w*hb.w;
                }
            }
            #pragma unroll
            for (int g=0;g<GPB;g++) outT[o][g] = acc[g];
        }
        __syncthreads();
        if (tid < LAT){
            const int l = tid;
            #pragma unroll
            for (int g=0;g<GPB;g++){
                const float m = outT[l][g];
                const float s = outT[l+LAT][g];
                const float gate = 1.f/(1.f + expf(-s));
                zT[l][g] = gate*zT[l][g] + (1.f-gate)*m;
                ld[g] += logf(gate + 1e-8f);
            }
        }
        __syncthreads();
    }

    #pragma unroll
    for (int q=0;q<4;q++){
        int idx = q*256 + tid;
        int g = idx & 7, l = idx >> 3;
        zK[(size_t)(g0+g)*LAT + l] = zT[l][g];
    }
    if (tid < LAT){
        #pragma unroll
        for (int g=0;g<GPB;g++) outT[tid][g] = ld[g];
    }
    __syncthreads();
    for (int st=64; st>0; st>>=1){
        if (tid < st){
            #pragma unroll
            for (int g=0;g<GPB;g++) outT[tid][g] += outT[tid+st][g];
        }
        __syncthreads();
    }
    if (tid < GPB) sld[g0 + tid] = outT[0][tid];
}

// ---------------- edge-logits symmetrize ----------------

__global__ void k_sym(const float* __restrict__ raw, float* __restrict__ outp){
    int idx = blockIdx.x*256 + threadIdx.x;
    const int total = NB*MA*MA;
    if (idx >= total) return;
    int b = idx / (MA*MA);
    int rem = idx - b*(MA*MA);
    int i = rem / MA;
    int j = rem - i*MA;
    const size_t base = (size_t)b*(MA*MA*NEF_);
    const float4 a  = *(const float4*)(raw + base + (size_t)(i*MA + j)*NEF_);
    const float4 bt = *(const float4*)(raw + base + (size_t)(j*MA + i)*NEF_);
    float4 r;
    r.x = (a.x + bt.x)*0.5f;
    r.y = (a.y + bt.y)*0.5f;
    r.z = (a.z + bt.z)*0.5f;
    r.w = (a.w + bt.w)*0.5f;
    *(float4*)(outp + base + (size_t)(i*MA + j)*NEF_) = r;
}

// ---------------- launch ----------------

extern "C" void kernel_launch(void* const* d_in, const int* in_sizes, int n_in,
                              void* d_out, int out_size, void* d_ws, size_t ws_size,
                              hipStream_t stream){
    (void)in_sizes; (void)n_in; (void)out_size; (void)ws_size;
    const int*   x        = (const int*)d_in[0];
    const int*   eidx     = (const int*)d_in[1];
    const int*   eattr    = (const int*)d_in[2];
    const int*   batch    = (const int*)d_in[3];
    const float* eps      = (const float*)d_in[4];
    const float* node_emb = (const float*)d_in[5];
    const float* edge_emb = (const float*)d_in[6];
    const float* conv_w1  = (const float*)d_in[7];
    const float* conv_b1  = (const float*)d_in[8];
    const float* conv_w2  = (const float*)d_in[9];
    const float* conv_b2  = (const float*)d_in[10];
    const float* mu_w     = (const float*)d_in[11];
    const float* mu_b     = (const float*)d_in[12];
    const float* lv_w     = (const float*)d_in[13];
    const float* lv_b     = (const float*)d_in[14];
    const float* fw1      = (const float*)d_in[15];
    const float* fb1      = (const float*)d_in[16];
    const float* fw2      = (const float*)d_in[17];
    const float* fb2      = (const float*)d_in[18];
    const float* dn_w1    = (const float*)d_in[19];
    const float* dn_b1    = (const float*)d_in[20];
    const float* dn_w2    = (const float*)d_in[21];
    const float* dn_b2    = (const float*)d_in[22];
    const float* de_w1    = (const float*)d_in[23];
    const float* de_b1    = (const float*)d_in[24];
    const float* de_w2    = (const float*)d_in[25];
    const float* de_b2    = (const float*)d_in[26];

    float* out = (float*)d_out;
    const size_t off_node = 0;
    const size_t off_edge = (size_t)NB*MA*NNF_;
    const size_t off_mu   = off_edge + (size_t)NB*MA*MA*NEF_;
    const size_t off_lv   = off_mu + (size_t)NB*LAT;
    const size_t off_z0   = off_lv + (size_t)NB*LAT;
    const size_t off_zk   = off_z0 + (size_t)NB*LAT;
    const size_t off_sld  = off_zk + (size_t)NB*LAT;

    char* p = (char*)d_ws;
    auto alloc = [&](size_t bytes)->char*{ char* r = p; p += (bytes + 255) & ~(size_t)255; return r; };
    uint32_t* h_pk  = (uint32_t*)alloc((size_t)N_NODES*HIDDEN*4);
    uint32_t* t_pk  = (uint32_t*)alloc((size_t)N_NODES*HIDDEN*4);  // also reused as edge_raw fp32 later
    int*   offs   = (int*)  alloc((size_t)(N_NODES+1)*4);
    int*   cursor = (int*)  alloc((size_t)N_NODES*4);
    int*   epack  = (int*)  alloc((size_t)N_EDGES*4);
    int*   gstart = (int*)  alloc((size_t)NB*4);
    int*   gcnt   = (int*)  alloc((size_t)NB*4);
    float* hg     = (float*)alloc((size_t)NB*HIDDEN*4);
    uint32_t* cw1pk = (uint32_t*)alloc((size_t)4*HIDDEN*HIDDEN*4);
    uint32_t* cw2pk = (uint32_t*)alloc((size_t)4*HIDDEN*HIDDEN*4);
    uint16_t* dnw1b = (uint16_t*)alloc((size_t)256*LAT*2);
    uint16_t* dnw2b = (uint16_t*)alloc((size_t)MA*NNF_*256*2);
    uint16_t* dew1b = (uint16_t*)alloc((size_t)512*LAT*2);
    uint16_t* dew2b = (uint16_t*)alloc((size_t)MA*MA*NEF_*512*2);
    uint16_t* zkb   = (uint16_t*)alloc((size_t)NB*LAT*2);
    uint16_t* hnb   = (uint16_t*)alloc((size_t)NB*256*2);
    uint16_t* heb   = (uint16_t*)alloc((size_t)NB*512*2);
    float* edge_raw = (float*)t_pk;   // alias: trunk done before decoder uses it

    const int* esrc = eidx;
    const int* edst = eidx + N_EDGES;

    // weight conversions
    k_cvt_pack<<<(4*HIDDEN*HIDDEN+255)/256, 256, 0, stream>>>(conv_w1, cw1pk, 4*HIDDEN*HIDDEN);
    k_cvt_pack<<<(4*HIDDEN*HIDDEN+255)/256, 256, 0, stream>>>(conv_w2, cw2pk, 4*HIDDEN*HIDDEN);
    k_cvt_b16<<<(256*LAT+255)/256, 256, 0, stream>>>(dn_w1, dnw1b, 256*LAT);
    k_cvt_b16<<<(MA*NNF_*256+255)/256, 256, 0, stream>>>(dn_w2, dnw2b, MA*NNF_*256);
    k_cvt_b16<<<(512*LAT+255)/256, 256, 0, stream>>>(de_w1, dew1b, 512*LAT);
    k_cvt_b16<<<(MA*MA*NEF_*512+255)/256, 256, 0, stream>>>(de_w2, dew2b, MA*MA*NEF_*512);

    k_init   <<<(N_NODES+255)/256, 256, 0, stream>>>(cursor, gstart, gcnt);
    k_embed  <<<N_NODES, HIDDEN, 0, stream>>>(x, node_emb, h_pk);
    k_deg    <<<(N_EDGES+255)/256, 256, 0, stream>>>(edst, cursor);
    k_meta   <<<(N_NODES+255)/256, 256, 0, stream>>>(batch, gstart, gcnt);
    k_scan   <<<1, 1024, 0, stream>>>(cursor, offs);
    k_scatter<<<(N_EDGES+255)/256, 256, 0, stream>>>(esrc, edst, eattr, offs, cursor, epack);

    const size_t SM = 65536;
    for (int k=0;k<4;k++){
        k_aggr<<<N_NODES, HIDDEN, 0, stream>>>(h_pk, edge_emb, offs, epack, t_pk);
        mfma_gemm<1,0><<<dim3(1, N_NODES/64), 256, SM, stream>>>(
            t_pk, cw1pk + (size_t)k*HIDDEN*HIDDEN, conv_b1 + (size_t)k*HIDDEN,
            t_pk, N_NODES, HIDDEN, HIDDEN, 1);
        mfma_gemm<1,0><<<dim3(1, N_NODES/64), 256, SM, stream>>>(
            t_pk, cw2pk + (size_t)k*HIDDEN*HIDDEN, conv_b2 + (size_t)k*HIDDEN,
            h_pk, N_NODES, HIDDEN, HIDDEN, 1);
    }

    k_pool<<<NB, HIDDEN, 0, stream>>>(h_pk, gstart, gcnt, hg);
    k_mulv<<<NB, LAT, 0, stream>>>(hg, mu_w, mu_b, lv_w, lv_b, eps,
                                   out+off_mu, out+off_lv, out+off_z0);
    k_flows<<<NB/GPB, 256, 0, stream>>>(out+off_z0, fw1, fb1, fw2, fb2,
                                        out+off_zk, out+off_sld);
    k_cvt_b16<<<(NB*LAT+255)/256, 256, 0, stream>>>(out+off_zk, zkb, NB*LAT);

    // decoders (plain bf16 MFMA)
    mfma_gemm<0,1><<<dim3(1, NB/64), 256, SM, stream>>>(zkb, dnw1b, dn_b1, hnb, NB, 256, LAT, 1);
    mfma_gemm<0,2><<<dim3(6, NB/64), 256, SM, stream>>>(hnb, dnw2b, dn_b2, out+off_node, NB, MA*NNF_, 256, 0);
    mfma_gemm<0,1><<<dim3(2, NB/64), 256, SM, stream>>>(zkb, dew1b, de_b1, heb, NB, 512, LAT, 1);
    mfma_gemm<0,2><<<dim3(23, NB/64), 256, SM, stream>>>(heb, dew2b, de_b2, edge_raw, NB, MA*MA*NEF_, 512, 0);
    k_sym<<<(NB*MA*MA + 255)/256, 256, 0, stream>>>(edge_raw, out + off_edge);
}